// Round 1
// 692.482 us; speedup vs baseline: 1.0436x; 1.0436x over previous
//
#include <hip/hip_runtime.h>

// Problem constants (fixed by reference): B=4, S=2048 -> N_TOK=8192; IN=OUT=4096; POOLS=128; top_k=2.
#define K_DIM  4096
#define N_OUT  4096
#define N_TOK  8192
#define N_POOL 128

typedef __bf16 bf16x8 __attribute__((ext_vector_type(8)));
typedef float  f32x4  __attribute__((ext_vector_type(4)));
typedef unsigned short u16x8 __attribute__((ext_vector_type(8)));

__device__ __forceinline__ unsigned short f2bf(float f) {
    union { float f; unsigned u; } v; v.f = f;
    unsigned r = v.u + 0x7fffu + ((v.u >> 16) & 1u);   // RNE
    return (unsigned short)(r >> 16);
}
__device__ __forceinline__ float bf2f(unsigned short b) {
    union { unsigned u; float f; } v; v.u = ((unsigned)b) << 16;
    return v.f;
}

// ---------------- kernel 1: w0 fp32 -> bf16 ----------------
__global__ __launch_bounds__(256) void k_convert_w0(const float* __restrict__ w0,
                                                    unsigned short* __restrict__ w0b) {
    size_t base = ((size_t)blockIdx.x * 256 + threadIdx.x) * 8;
    float4 a = *(const float4*)(w0 + base);
    float4 b = *(const float4*)(w0 + base + 4);
    u16x8 r;
    r[0] = f2bf(a.x); r[1] = f2bf(a.y); r[2] = f2bf(a.z); r[3] = f2bf(a.w);
    r[4] = f2bf(b.x); r[5] = f2bf(b.y); r[6] = f2bf(b.z); r[7] = f2bf(b.w);
    *(u16x8*)(w0b + base) = r;
}

// ---------------- kernel 1c: wr fp32 -> hi/lo bf16 split ----------------
// wrh = bf16(wr); wrl = bf16(wr - wrh). wrh+wrl carries ~16 mantissa bits, so the
// 3-product MFMA logits (xh*wh + xh*wl + xl*wh) land within ~1e-5 of fp32.
__global__ __launch_bounds__(256) void k_split_wr(const float* __restrict__ wr,
                                                  unsigned short* __restrict__ wrh,
                                                  unsigned short* __restrict__ wrl) {
    size_t base = ((size_t)blockIdx.x * 256 + threadIdx.x) * 4;
    float4 a = *(const float4*)(wr + base);
    ushort4 h, l;
    h.x = f2bf(a.x); h.y = f2bf(a.y); h.z = f2bf(a.z); h.w = f2bf(a.w);
    l.x = f2bf(a.x - bf2f(h.x)); l.y = f2bf(a.y - bf2f(h.y));
    l.z = f2bf(a.z - bf2f(h.z)); l.w = f2bf(a.w - bf2f(h.w));
    *(ushort4*)(wrh + base) = h;
    *(ushort4*)(wrl + base) = l;
}

// ---------------- kernel 1b: u [OUT,POOLS] -> uT [POOLS,OUT] ----------------
__global__ __launch_bounds__(256) void k_transpose_u(const float* __restrict__ u,
                                                     float* __restrict__ uT) {
    __shared__ float t[32][65];
    const int o0 = blockIdx.x * 64, p0 = blockIdx.y * 32;
    const int tid = threadIdx.x;
#pragma unroll
    for (int it = 0; it < 8; it++) {
        int o = (tid >> 5) + it * 8;
        t[tid & 31][o] = u[(size_t)(o0 + o) * N_POOL + p0 + (tid & 31)];
    }
    __syncthreads();
#pragma unroll
    for (int it = 0; it < 8; it++) {
        int p = (tid >> 6) + it * 4;
        uT[(size_t)(p0 + p) * N_OUT + o0 + (tid & 63)] = t[p][tid & 63];
    }
}

// ---------------- kernel 2: MFMA router ----------------
// Logits via matrix cores in split-bf16 (3 accumulated products ~ fp32 accuracy).
// Block: 512 threads (8 waves), 32 tokens x 128 pools, BK=64, grid 256.
// LDS tiles XOR-swizzled at 16B-chunk granularity (same scheme as k_gemm): LDS[r][c]
// holds global chunk c^(r&7). B staged via global_load_lds with pre-swizzled source;
// A reg-staged (fp32 x -> xh/xl bf16) with swizzled ds_write; xh also emitted to xb.
// Near-ties (v2-v3 < TAU) get an exact fp32 recompute of candidate pools so the
// top-2 SET (order is irrelevant: vals are unused, sum is symmetric) matches fp32.
#define RTK 64
#define TAU 0.01f

__global__ __launch_bounds__(512) void k_router(const float* __restrict__ x,
                                                const float* __restrict__ wr,
                                                const unsigned short* __restrict__ wrh,
                                                const unsigned short* __restrict__ wrl,
                                                const float* __restrict__ svh,
                                                unsigned short* __restrict__ xb,
                                                int* __restrict__ idxp,
                                                float* __restrict__ dotp) {
    __shared__ __attribute__((aligned(16))) unsigned short Ah[32 * RTK];     // 4 KB
    __shared__ __attribute__((aligned(16))) unsigned short Al[32 * RTK];     // 4 KB
    __shared__ __attribute__((aligned(16))) unsigned short Bh[N_POOL * RTK]; // 16 KB
    __shared__ __attribute__((aligned(16))) unsigned short Bl[N_POOL * RTK]; // 16 KB
    __shared__ float lg[32][N_POOL + 1];   // 16.5 KB, stride 129: conflict-free scan
    __shared__ float thr2[32];
    __shared__ int   flg[32];
    __shared__ int   sel[32][2];

    const int tid  = threadIdx.x;
    const int lane = tid & 63;
    const int w    = tid >> 6;          // wave 0..7
    const int wm   = w & 1;             // m-tile: tokens 16*wm..+15
    const int wn   = w >> 1;            // pool group: 32*wn..+31
    const int lrow = lane & 15, lquad = lane >> 4;
    const size_t m0 = (size_t)blockIdx.x * 32;

    // A staging: thread covers token=tid>>4, 4 k at (tid&15)*4 (half a 16B chunk)
    const int atok  = tid >> 4;
    const int akoff = (tid & 15) * 4;
    const int aswz  = ((((tid & 15) >> 1) ^ (atok & 7)) * 8) + (tid & 1) * 4;

    // B staging: pass i covers row brow+64i, chunk tid&7 (source pre-swizzled)
    const int brow = tid >> 3;

    float4 x_pf = *(const float4*)(x + (m0 + atok) * K_DIM + akoff);

    f32x4 acc[2] = {};

    for (int k0 = 0; k0 < K_DIM; k0 += RTK) {
        __syncthreads();   // prev tile's fragment readers done
        {
            ushort4 h, l;
            h.x = f2bf(x_pf.x); h.y = f2bf(x_pf.y); h.z = f2bf(x_pf.z); h.w = f2bf(x_pf.w);
            l.x = f2bf(x_pf.x - bf2f(h.x)); l.y = f2bf(x_pf.y - bf2f(h.y));
            l.z = f2bf(x_pf.z - bf2f(h.z)); l.w = f2bf(x_pf.w - bf2f(h.w));
            *(ushort4*)(xb + (m0 + atok) * K_DIM + k0 + akoff) = h;   // bf16 x for k_gemm/dots
            *(ushort4*)(&Ah[atok * RTK + aswz]) = h;
            *(ushort4*)(&Al[atok * RTK + aswz]) = l;
        }
#pragma unroll
        for (int i = 0; i < 2; i++) {
            const int r = brow + i * 64;
            const int c = (tid & 7) ^ (r & 7);
            __builtin_amdgcn_global_load_lds(
                (const __attribute__((address_space(1))) void*)(wrh + (size_t)r * K_DIM + k0 + c * 8),
                (__attribute__((address_space(3))) void*)(Bh + i * 4096 + tid * 8), 16, 0, 0);
            __builtin_amdgcn_global_load_lds(
                (const __attribute__((address_space(1))) void*)(wrl + (size_t)r * K_DIM + k0 + c * 8),
                (__attribute__((address_space(3))) void*)(Bl + i * 4096 + tid * 8), 16, 0, 0);
        }
        __syncthreads();   // compiler drains vmcnt/lgkm: tiles ready
        if (k0 + RTK < K_DIM)
            x_pf = *(const float4*)(x + (m0 + atok) * K_DIM + k0 + RTK + akoff);
#pragma unroll
        for (int ks = 0; ks < 2; ks++) {
            const int cs = ((ks * 4 + lquad) ^ (lrow & 7)) * 8;
            bf16x8 ah = *(const bf16x8*)&Ah[(wm * 16 + lrow) * RTK + cs];
            bf16x8 al = *(const bf16x8*)&Al[(wm * 16 + lrow) * RTK + cs];
#pragma unroll
            for (int nt = 0; nt < 2; nt++) {
                bf16x8 bh = *(const bf16x8*)&Bh[(wn * 32 + nt * 16 + lrow) * RTK + cs];
                bf16x8 bl = *(const bf16x8*)&Bl[(wn * 32 + nt * 16 + lrow) * RTK + cs];
                acc[nt] = __builtin_amdgcn_mfma_f32_16x16x32_bf16(ah, bh, acc[nt], 0, 0, 0);
                acc[nt] = __builtin_amdgcn_mfma_f32_16x16x32_bf16(ah, bl, acc[nt], 0, 0, 0);
                acc[nt] = __builtin_amdgcn_mfma_f32_16x16x32_bf16(al, bh, acc[nt], 0, 0, 0);
            }
        }
    }

    // logits -> LDS (C/D layout: col=lane&15 -> pool, row=(lane>>4)*4+reg -> token)
#pragma unroll
    for (int nt = 0; nt < 2; nt++)
#pragma unroll
        for (int r = 0; r < 4; r++)
            lg[wm * 16 + lquad * 4 + r][wn * 32 + nt * 16 + lrow] = acc[nt][r];
    __syncthreads();

    // serial top-3 per token; strict '>' matches jax.lax.top_k tie rule
    if (tid < 32) {
        float v1 = -3.4e38f, v2 = -3.4e38f, v3 = -3.4e38f; int i1 = 0, i2 = 0;
        for (int p = 0; p < N_POOL; p++) {
            float v = lg[tid][p];
            if (v > v1)      { v3 = v2; v2 = v1; i2 = i1; v1 = v; i1 = p; }
            else if (v > v2) { v3 = v2; v2 = v;  i2 = p; }
            else if (v > v3) { v3 = v; }
        }
        sel[tid][0] = i1; sel[tid][1] = i2;
        thr2[tid] = v2 - TAU;
        flg[tid]  = (v2 - v3 < TAU) ? 1 : 0;
    }
    __syncthreads();

    // near-tie fallback: wave 0 recomputes fp32 logits for candidate pools.
    // bf-split error ~1e-5 << TAU, so non-candidates (< v2-TAU) provably can't be top-2.
    if (w == 0) {
        for (int s = 0; s < 32; s++) {
            if (!flg[s]) continue;
            const float th = thr2[s];
            unsigned long long c0 = __ballot(lg[s][lane] >= th);
            unsigned long long c1 = __ballot(lg[s][64 + lane] >= th);
            float v1 = -3.4e38f, v2 = -3.4e38f; int i1 = 0, i2 = 0;
            const float* xr = x + (m0 + s) * K_DIM;
            for (int half = 0; half < 2; half++) {
                unsigned long long m = half ? c1 : c0;
                while (m) {
                    const int p = (half ? 64 : 0) + __ffsll(m) - 1;
                    m &= m - 1;
                    const float* wp = wr + (size_t)p * K_DIM;
                    float d = 0.f;
#pragma unroll 8
                    for (int it = 0; it < 64; it++)
                        d += xr[it * 64 + lane] * wp[it * 64 + lane];
#pragma unroll
                    for (int off = 32; off > 0; off >>= 1) d += __shfl_down(d, off);
                    d = __shfl(d, 0);
                    if (d > v1)      { v2 = v1; i2 = i1; v1 = d; i1 = p; }
                    else if (d > v2) { v2 = d; i2 = p; }
                }
            }
            if (lane == 0) { sel[s][0] = i1; sel[s][1] = i2; }
        }
    }
    __syncthreads();

    if (tid < 32) {
        idxp[(m0 + tid) * 2 + 0] = sel[tid][0];
        idxp[(m0 + tid) * 2 + 1] = sel[tid][1];
    }

    // svh dots: one wave per token (8 waves round-robin); both top-2 rows share the x read
    for (int s = w; s < 32; s += 8) {
        const size_t n = m0 + s;
        const int e0 = sel[s][0], e1 = sel[s][1];
        float d0 = 0.f, d1 = 0.f;
#pragma unroll
        for (int it = 0; it < 8; it++) {
            const int e = (it * 64 + lane) * 8;
            u16x8 xv = *(const u16x8*)(xb + n * K_DIM + e);
            float4 s0 = *(const float4*)(svh + (size_t)e0 * K_DIM + e);
            float4 s1 = *(const float4*)(svh + (size_t)e0 * K_DIM + e + 4);
            float4 s2 = *(const float4*)(svh + (size_t)e1 * K_DIM + e);
            float4 s3 = *(const float4*)(svh + (size_t)e1 * K_DIM + e + 4);
            float x0 = bf2f(xv[0]), x1 = bf2f(xv[1]), x2 = bf2f(xv[2]), x3 = bf2f(xv[3]);
            float x4 = bf2f(xv[4]), x5 = bf2f(xv[5]), x6 = bf2f(xv[6]), x7 = bf2f(xv[7]);
            d0 += x0*s0.x + x1*s0.y + x2*s0.z + x3*s0.w + x4*s1.x + x5*s1.y + x6*s1.z + x7*s1.w;
            d1 += x0*s2.x + x1*s2.y + x2*s2.z + x3*s2.w + x4*s3.x + x5*s3.y + x6*s3.z + x7*s3.w;
        }
#pragma unroll
        for (int off = 32; off > 0; off >>= 1) {
            d0 += __shfl_down(d0, off);
            d1 += __shfl_down(d1, off);
        }
        if (lane == 0) { dotp[n * 2 + 0] = d0; dotp[n * 2 + 1] = d1; }
    }
}

// ---------------- kernel 3: bf16 MFMA GEMM + fused bias/expert epilogue (unchanged) ----------------
__global__ __launch_bounds__(256) void k_gemm(const unsigned short* __restrict__ xb,
                                              const unsigned short* __restrict__ w0b,
                                              const float* __restrict__ b0,
                                              const float* __restrict__ uT,
                                              const int* __restrict__ idxp,
                                              const float* __restrict__ dotp,
                                              float* __restrict__ out) {
    __shared__ unsigned short Als[128 * 64];   // 16 KB
    __shared__ unsigned short Bls[128 * 64];   // 16 KB

    const int tid  = threadIdx.x;
    const int lane = tid & 63;
    const int wv   = tid >> 6;
    const int wm   = wv & 1, wn = wv >> 1;
    const int lrow = lane & 15, lquad = lane >> 4;
    const size_t m0 = (size_t)blockIdx.y * 128;   // token tile
    const size_t n0 = (size_t)blockIdx.x * 128;   // out-feature tile

    const int srow   = tid >> 3;
    const int xchunk = (tid & 7) ^ (srow & 7);
    const unsigned short* ag = xb  + (m0 + srow) * K_DIM + xchunk * 8;
    const unsigned short* bg = w0b + (n0 + srow) * K_DIM + xchunk * 8;
    unsigned short* al = Als + tid * 8;
    unsigned short* bl = Bls + tid * 8;

    f32x4 acc[4][4] = {};

    for (int k0 = 0; k0 < K_DIM; k0 += 64) {
        __syncthreads();
#pragma unroll
        for (int i = 0; i < 4; i++) {
            __builtin_amdgcn_global_load_lds(
                (const __attribute__((address_space(1))) void*)(ag + (size_t)i * 32 * K_DIM + k0),
                (__attribute__((address_space(3))) void*)(al + i * 2048), 16, 0, 0);
            __builtin_amdgcn_global_load_lds(
                (const __attribute__((address_space(1))) void*)(bg + (size_t)i * 32 * K_DIM + k0),
                (__attribute__((address_space(3))) void*)(bl + i * 2048), 16, 0, 0);
        }
        __syncthreads();
#pragma unroll
        for (int ks = 0; ks < 2; ks++) {
            bf16x8 af[4], bfr[4];
#pragma unroll
            for (int t = 0; t < 4; t++)
                af[t] = *(const bf16x8*)&Als[(wm * 64 + t * 16 + lrow) * 64 +
                                             (((ks * 4 + lquad) ^ (lrow & 7)) * 8)];
#pragma unroll
            for (int t = 0; t < 4; t++)
                bfr[t] = *(const bf16x8*)&Bls[(wn * 64 + t * 16 + lrow) * 64 +
                                              (((ks * 4 + lquad) ^ (lrow & 7)) * 8)];
#pragma unroll
            for (int mt = 0; mt < 4; mt++)
#pragma unroll
                for (int nt = 0; nt < 4; nt++)
                    acc[mt][nt] = __builtin_amdgcn_mfma_f32_16x16x32_bf16(af[mt], bfr[nt], acc[mt][nt], 0, 0, 0);
        }
    }

#pragma unroll
    for (int mt = 0; mt < 4; mt++) {
        const size_t rb = m0 + wm * 64 + mt * 16 + lquad * 4;
#pragma unroll
        for (int r = 0; r < 4; r++) {
            const size_t gm = rb + r;
            const int e0 = idxp[gm * 2 + 0], e1 = idxp[gm * 2 + 1];
            const float dd0 = dotp[gm * 2 + 0], dd1 = dotp[gm * 2 + 1];
#pragma unroll
            for (int nt = 0; nt < 4; nt++) {
                const size_t gn = n0 + wn * 64 + nt * 16 + lrow;
                float vv = acc[mt][nt][r] + b0[gn]
                         + dd0 * uT[(size_t)e0 * N_OUT + gn] + dd1 * uT[(size_t)e1 * N_OUT + gn];
                out[gm * N_OUT + gn] = vv;
            }
        }
    }
}

extern "C" void kernel_launch(void* const* d_in, const int* in_sizes, int n_in,
                              void* d_out, int out_size, void* d_ws, size_t ws_size,
                              hipStream_t stream) {
    const float* x   = (const float*)d_in[0];  // [8192, 4096]
    const float* w0  = (const float*)d_in[1];  // [4096, 4096]
    const float* b0  = (const float*)d_in[2];  // [4096]
    const float* wr  = (const float*)d_in[3];  // [128, 4096]
    const float* u   = (const float*)d_in[4];  // [4096, 128]
    const float* svh = (const float*)d_in[5];  // [128, 4096]
    float* out = (float*)d_out;

    // workspace layout (~100.1 MiB total)
    char* ws = (char*)d_ws;
    unsigned short* xb  = (unsigned short*)ws;                       // 8192*4096*2  = 67108864 B
    unsigned short* w0b = (unsigned short*)(ws + 67108864);          // 4096*4096*2  = 33554432 B
    int*   idxp = (int*)(ws + 100663296);                            // 8192*2*4     = 65536 B
    float* dotp = (float*)(ws + 100663296 + 65536);                  // 8192*2*4     = 65536 B
    float* uTp  = (float*)(ws + 100663296 + 131072);                 // 128*4096*4   = 2097152 B
    unsigned short* wrh = (unsigned short*)(ws + 102891520);         // 128*4096*2   = 1048576 B
    unsigned short* wrl = (unsigned short*)(ws + 103940096);         // 128*4096*2   = 1048576 B

    k_convert_w0<<<dim3(16777216 / (256 * 8)), dim3(256), 0, stream>>>(w0, w0b);
    k_split_wr<<<dim3(N_POOL * K_DIM / (256 * 4)), dim3(256), 0, stream>>>(wr, wrh, wrl);
    k_transpose_u<<<dim3(N_OUT / 64, N_POOL / 32), dim3(256), 0, stream>>>(u, uTp);
    k_router<<<dim3(N_TOK / 32), dim3(512), 0, stream>>>(x, wr, wrh, wrl, svh, xb, idxp, dotp);
    k_gemm<<<dim3(N_OUT / 128, N_TOK / 128), dim3(256), 0, stream>>>(xb, w0b, b0, uTp, idxp, dotp, out);
}

// Round 2
// 680.875 us; speedup vs baseline: 1.0614x; 1.0170x over previous
//
#include <hip/hip_runtime.h>

// Problem constants (fixed by reference): B=4, S=2048 -> N_TOK=8192; IN=OUT=4096; POOLS=128; top_k=2.
#define K_DIM  4096
#define N_OUT  4096
#define N_TOK  8192
#define N_POOL 128

typedef __bf16 bf16x8 __attribute__((ext_vector_type(8)));
typedef float  f32x4  __attribute__((ext_vector_type(4)));
typedef unsigned short u16x8 __attribute__((ext_vector_type(8)));

__device__ __forceinline__ unsigned short f2bf(float f) {
    union { float f; unsigned u; } v; v.f = f;
    unsigned r = v.u + 0x7fffu + ((v.u >> 16) & 1u);   // RNE
    return (unsigned short)(r >> 16);
}
__device__ __forceinline__ float bf2f(unsigned short b) {
    union { unsigned u; float f; } v; v.u = ((unsigned)b) << 16;
    return v.f;
}

// ---------------- kernel 1: w0 fp32 -> bf16 ----------------
__global__ __launch_bounds__(256) void k_convert_w0(const float* __restrict__ w0,
                                                    unsigned short* __restrict__ w0b) {
    size_t base = ((size_t)blockIdx.x * 256 + threadIdx.x) * 8;
    float4 a = *(const float4*)(w0 + base);
    float4 b = *(const float4*)(w0 + base + 4);
    u16x8 r;
    r[0] = f2bf(a.x); r[1] = f2bf(a.y); r[2] = f2bf(a.z); r[3] = f2bf(a.w);
    r[4] = f2bf(b.x); r[5] = f2bf(b.y); r[6] = f2bf(b.z); r[7] = f2bf(b.w);
    *(u16x8*)(w0b + base) = r;
}

// ---------------- kernel 1c: wr fp32 -> hi/lo bf16 split ----------------
__global__ __launch_bounds__(256) void k_split_wr(const float* __restrict__ wr,
                                                  unsigned short* __restrict__ wrh,
                                                  unsigned short* __restrict__ wrl) {
    size_t base = ((size_t)blockIdx.x * 256 + threadIdx.x) * 4;
    float4 a = *(const float4*)(wr + base);
    ushort4 h, l;
    h.x = f2bf(a.x); h.y = f2bf(a.y); h.z = f2bf(a.z); h.w = f2bf(a.w);
    l.x = f2bf(a.x - bf2f(h.x)); l.y = f2bf(a.y - bf2f(h.y));
    l.z = f2bf(a.z - bf2f(h.z)); l.w = f2bf(a.w - bf2f(h.w));
    *(ushort4*)(wrh + base) = h;
    *(ushort4*)(wrl + base) = l;
}

// ---------------- kernel 1b: u [OUT,POOLS] -> uT [POOLS,OUT] ----------------
__global__ __launch_bounds__(256) void k_transpose_u(const float* __restrict__ u,
                                                     float* __restrict__ uT) {
    __shared__ float t[32][65];
    const int o0 = blockIdx.x * 64, p0 = blockIdx.y * 32;
    const int tid = threadIdx.x;
#pragma unroll
    for (int it = 0; it < 8; it++) {
        int o = (tid >> 5) + it * 8;
        t[tid & 31][o] = u[(size_t)(o0 + o) * N_POOL + p0 + (tid & 31)];
    }
    __syncthreads();
#pragma unroll
    for (int it = 0; it < 8; it++) {
        int p = (tid >> 6) + it * 4;
        uT[(size_t)(p0 + p) * N_OUT + o0 + (tid & 63)] = t[p][tid & 63];
    }
}

// ---------------- kernel 2: MFMA router (unchanged this round) ----------------
#define RTK 64
#define TAU 0.01f

__global__ __launch_bounds__(512) void k_router(const float* __restrict__ x,
                                                const float* __restrict__ wr,
                                                const unsigned short* __restrict__ wrh,
                                                const unsigned short* __restrict__ wrl,
                                                const float* __restrict__ svh,
                                                unsigned short* __restrict__ xb,
                                                int* __restrict__ idxp,
                                                float* __restrict__ dotp) {
    __shared__ __attribute__((aligned(16))) unsigned short Ah[32 * RTK];     // 4 KB
    __shared__ __attribute__((aligned(16))) unsigned short Al[32 * RTK];     // 4 KB
    __shared__ __attribute__((aligned(16))) unsigned short Bh[N_POOL * RTK]; // 16 KB
    __shared__ __attribute__((aligned(16))) unsigned short Bl[N_POOL * RTK]; // 16 KB
    __shared__ float lg[32][N_POOL + 1];   // 16.5 KB, stride 129: conflict-free scan
    __shared__ float thr2[32];
    __shared__ int   flg[32];
    __shared__ int   sel[32][2];

    const int tid  = threadIdx.x;
    const int lane = tid & 63;
    const int w    = tid >> 6;          // wave 0..7
    const int wm   = w & 1;             // m-tile: tokens 16*wm..+15
    const int wn   = w >> 1;            // pool group: 32*wn..+31
    const int lrow = lane & 15, lquad = lane >> 4;
    const size_t m0 = (size_t)blockIdx.x * 32;

    const int atok  = tid >> 4;
    const int akoff = (tid & 15) * 4;
    const int aswz  = ((((tid & 15) >> 1) ^ (atok & 7)) * 8) + (tid & 1) * 4;

    const int brow = tid >> 3;

    float4 x_pf = *(const float4*)(x + (m0 + atok) * K_DIM + akoff);

    f32x4 acc[2] = {};

    for (int k0 = 0; k0 < K_DIM; k0 += RTK) {
        __syncthreads();   // prev tile's fragment readers done
        {
            ushort4 h, l;
            h.x = f2bf(x_pf.x); h.y = f2bf(x_pf.y); h.z = f2bf(x_pf.z); h.w = f2bf(x_pf.w);
            l.x = f2bf(x_pf.x - bf2f(h.x)); l.y = f2bf(x_pf.y - bf2f(h.y));
            l.z = f2bf(x_pf.z - bf2f(h.z)); l.w = f2bf(x_pf.w - bf2f(h.w));
            *(ushort4*)(xb + (m0 + atok) * K_DIM + k0 + akoff) = h;   // bf16 x for k_gemm/dots
            *(ushort4*)(&Ah[atok * RTK + aswz]) = h;
            *(ushort4*)(&Al[atok * RTK + aswz]) = l;
        }
#pragma unroll
        for (int i = 0; i < 2; i++) {
            const int r = brow + i * 64;
            const int c = (tid & 7) ^ (r & 7);
            __builtin_amdgcn_global_load_lds(
                (const __attribute__((address_space(1))) void*)(wrh + (size_t)r * K_DIM + k0 + c * 8),
                (__attribute__((address_space(3))) void*)(Bh + i * 4096 + tid * 8), 16, 0, 0);
            __builtin_amdgcn_global_load_lds(
                (const __attribute__((address_space(1))) void*)(wrl + (size_t)r * K_DIM + k0 + c * 8),
                (__attribute__((address_space(3))) void*)(Bl + i * 4096 + tid * 8), 16, 0, 0);
        }
        __syncthreads();   // tiles ready
        if (k0 + RTK < K_DIM)
            x_pf = *(const float4*)(x + (m0 + atok) * K_DIM + k0 + RTK + akoff);
#pragma unroll
        for (int ks = 0; ks < 2; ks++) {
            const int cs = ((ks * 4 + lquad) ^ (lrow & 7)) * 8;
            bf16x8 ah = *(const bf16x8*)&Ah[(wm * 16 + lrow) * RTK + cs];
            bf16x8 al = *(const bf16x8*)&Al[(wm * 16 + lrow) * RTK + cs];
#pragma unroll
            for (int nt = 0; nt < 2; nt++) {
                bf16x8 bh = *(const bf16x8*)&Bh[(wn * 32 + nt * 16 + lrow) * RTK + cs];
                bf16x8 bl = *(const bf16x8*)&Bl[(wn * 32 + nt * 16 + lrow) * RTK + cs];
                acc[nt] = __builtin_amdgcn_mfma_f32_16x16x32_bf16(ah, bh, acc[nt], 0, 0, 0);
                acc[nt] = __builtin_amdgcn_mfma_f32_16x16x32_bf16(ah, bl, acc[nt], 0, 0, 0);
                acc[nt] = __builtin_amdgcn_mfma_f32_16x16x32_bf16(al, bh, acc[nt], 0, 0, 0);
            }
        }
    }

    // logits -> LDS (C/D layout: col=lane&15 -> pool, row=(lane>>4)*4+reg -> token)
#pragma unroll
    for (int nt = 0; nt < 2; nt++)
#pragma unroll
        for (int r = 0; r < 4; r++)
            lg[wm * 16 + lquad * 4 + r][wn * 32 + nt * 16 + lrow] = acc[nt][r];
    __syncthreads();

    if (tid < 32) {
        float v1 = -3.4e38f, v2 = -3.4e38f, v3 = -3.4e38f; int i1 = 0, i2 = 0;
        for (int p = 0; p < N_POOL; p++) {
            float v = lg[tid][p];
            if (v > v1)      { v3 = v2; v2 = v1; i2 = i1; v1 = v; i1 = p; }
            else if (v > v2) { v3 = v2; v2 = v;  i2 = p; }
            else if (v > v3) { v3 = v; }
        }
        sel[tid][0] = i1; sel[tid][1] = i2;
        thr2[tid] = v2 - TAU;
        flg[tid]  = (v2 - v3 < TAU) ? 1 : 0;
    }
    __syncthreads();

    if (w == 0) {
        for (int s = 0; s < 32; s++) {
            if (!flg[s]) continue;
            const float th = thr2[s];
            unsigned long long c0 = __ballot(lg[s][lane] >= th);
            unsigned long long c1 = __ballot(lg[s][64 + lane] >= th);
            float v1 = -3.4e38f, v2 = -3.4e38f; int i1 = 0, i2 = 0;
            const float* xr = x + (m0 + s) * K_DIM;
            for (int half = 0; half < 2; half++) {
                unsigned long long m = half ? c1 : c0;
                while (m) {
                    const int p = (half ? 64 : 0) + __ffsll(m) - 1;
                    m &= m - 1;
                    const float* wp = wr + (size_t)p * K_DIM;
                    float d = 0.f;
#pragma unroll 8
                    for (int it = 0; it < 64; it++)
                        d += xr[it * 64 + lane] * wp[it * 64 + lane];
#pragma unroll
                    for (int off = 32; off > 0; off >>= 1) d += __shfl_down(d, off);
                    d = __shfl(d, 0);
                    if (d > v1)      { v2 = v1; i2 = i1; v1 = d; i1 = p; }
                    else if (d > v2) { v2 = d; i2 = p; }
                }
            }
            if (lane == 0) { sel[s][0] = i1; sel[s][1] = i2; }
        }
    }
    __syncthreads();

    if (tid < 32) {
        idxp[(m0 + tid) * 2 + 0] = sel[tid][0];
        idxp[(m0 + tid) * 2 + 1] = sel[tid][1];
    }

    for (int s = w; s < 32; s += 8) {
        const size_t n = m0 + s;
        const int e0 = sel[s][0], e1 = sel[s][1];
        float d0 = 0.f, d1 = 0.f;
#pragma unroll
        for (int it = 0; it < 8; it++) {
            const int e = (it * 64 + lane) * 8;
            u16x8 xv = *(const u16x8*)(xb + n * K_DIM + e);
            float4 s0 = *(const float4*)(svh + (size_t)e0 * K_DIM + e);
            float4 s1 = *(const float4*)(svh + (size_t)e0 * K_DIM + e + 4);
            float4 s2 = *(const float4*)(svh + (size_t)e1 * K_DIM + e);
            float4 s3 = *(const float4*)(svh + (size_t)e1 * K_DIM + e + 4);
            float x0 = bf2f(xv[0]), x1 = bf2f(xv[1]), x2 = bf2f(xv[2]), x3 = bf2f(xv[3]);
            float x4 = bf2f(xv[4]), x5 = bf2f(xv[5]), x6 = bf2f(xv[6]), x7 = bf2f(xv[7]);
            d0 += x0*s0.x + x1*s0.y + x2*s0.z + x3*s0.w + x4*s1.x + x5*s1.y + x6*s1.z + x7*s1.w;
            d1 += x0*s2.x + x1*s2.y + x2*s2.z + x3*s2.w + x4*s3.x + x5*s3.y + x6*s3.z + x7*s3.w;
        }
#pragma unroll
        for (int off = 32; off > 0; off >>= 1) {
            d0 += __shfl_down(d0, off);
            d1 += __shfl_down(d1, off);
        }
        if (lane == 0) { dotp[n * 2 + 0] = d0; dotp[n * 2 + 1] = d1; }
    }
}

// ---------------- kernel 3: 256x256 double-buffered bf16 MFMA GEMM, counted-vmcnt pipeline ----
// BM=BN=256, BK=64, 512 threads = 8 waves (2 m x 4 n), per-wave 128x64 output (acc[8][4]).
// LDS 128 KiB: A/B each 2 x 256x64 bf16. Chunk-XOR swizzle (phys_chunk = c ^ (row&7)) applied
// on the pre-swizzled global source of global_load_lds and inverted in fragment reads.
// Pipeline per tile t: [vmcnt(8); barrier] compute(buf[t&1]) [barrier] stage(t+2 -> buf[t&1]).
// vmcnt(8) keeps stage(t+1)'s 8 loads in flight across the barrier (never drain to 0 in-loop).
// Bijective XCD swizzle on the 1D grid (nwg=512, 512%8==0).
__global__ __launch_bounds__(512) void k_gemm(const unsigned short* __restrict__ xb,
                                              const unsigned short* __restrict__ w0b,
                                              const float* __restrict__ b0,
                                              const float* __restrict__ uT,
                                              const int* __restrict__ idxp,
                                              const float* __restrict__ dotp,
                                              float* __restrict__ out) {
    __shared__ __attribute__((aligned(16))) unsigned short Als[2][256 * 64];  // 64 KB
    __shared__ __attribute__((aligned(16))) unsigned short Bls[2][256 * 64];  // 64 KB

    const int tid  = threadIdx.x;
    const int lane = tid & 63;
    const int w    = tid >> 6;
    const int wm   = w >> 2, wn = w & 3;          // 2 x 4 wave grid
    const int lrow = lane & 15, lquad = lane >> 4;

    // bijective XCD swizzle: blocks b == x (mod 8) get contiguous logical ids [x*64, x*64+64)
    const int lg = (blockIdx.x & 7) * 64 + (blockIdx.x >> 3);
    const size_t n0 = (size_t)(lg & 15) * 256;    // 16 N-tiles
    const size_t m0 = (size_t)(lg >> 4) * 256;    // 32 M-tiles

    // staging: thread covers rows srow + l*64 (l=0..3), 16B chunk (tid&7); source pre-swizzled
    const int srow   = tid >> 3;                  // 0..63
    const int xchunk = (tid & 7) ^ (srow & 7);
    const unsigned short* ag = xb  + (m0 + srow) * K_DIM + xchunk * 8;
    const unsigned short* bg = w0b + (n0 + srow) * K_DIM + xchunk * 8;

    f32x4 acc[8][4] = {};

#define STAGE(buf, k0)                                                                        \
    {                                                                                         \
        unsigned short* al = &Als[buf][tid * 8];                                              \
        unsigned short* bl = &Bls[buf][tid * 8];                                              \
        _Pragma("unroll")                                                                     \
        for (int l = 0; l < 4; l++) {                                                         \
            __builtin_amdgcn_global_load_lds(                                                 \
                (const __attribute__((address_space(1))) void*)(ag + (size_t)l * 64 * K_DIM + (k0)), \
                (__attribute__((address_space(3))) void*)(al + l * 4096), 16, 0, 0);          \
            __builtin_amdgcn_global_load_lds(                                                 \
                (const __attribute__((address_space(1))) void*)(bg + (size_t)l * 64 * K_DIM + (k0)), \
                (__attribute__((address_space(3))) void*)(bl + l * 4096), 16, 0, 0);          \
        }                                                                                     \
    }

#define COMPUTE(buf)                                                                          \
    {                                                                                         \
        _Pragma("unroll")                                                                     \
        for (int ks = 0; ks < 2; ks++) {                                                      \
            const int cs = ((ks * 4 + lquad) ^ (lrow & 7)) * 8;                               \
            bf16x8 bfv[4];                                                                    \
            _Pragma("unroll")                                                                 \
            for (int nt = 0; nt < 4; nt++)                                                    \
                bfv[nt] = *(const bf16x8*)&Bls[buf][(wn * 64 + nt * 16 + lrow) * 64 + cs];    \
            _Pragma("unroll")                                                                 \
            for (int mt = 0; mt < 8; mt++) {                                                  \
                bf16x8 av = *(const bf16x8*)&Als[buf][(wm * 128 + mt * 16 + lrow) * 64 + cs]; \
                _Pragma("unroll")                                                             \
                for (int nt = 0; nt < 4; nt++)                                                \
                    acc[mt][nt] = __builtin_amdgcn_mfma_f32_16x16x32_bf16(av, bfv[nt], acc[mt][nt], 0, 0, 0); \
            }                                                                                 \
        }                                                                                     \
    }

    // prologue: tiles 0 and 1 in flight
    STAGE(0, 0)
    STAGE(1, 64)

    // steady state: tiles 0..62
    for (int t = 0; t < 63; ++t) {
        asm volatile("s_waitcnt vmcnt(8)" ::: "memory");   // tile t landed; t+1 stays in flight
        __builtin_amdgcn_s_barrier();
        const int buf = t & 1;
        COMPUTE(buf)
        __builtin_amdgcn_s_barrier();                      // all reads of buf done
        if (t < 62) STAGE(buf, (t + 2) * 64)               // prefetch tile t+2 into freed buf
    }
    // tile 63: its loads are the only outstanding ones
    asm volatile("s_waitcnt vmcnt(0)" ::: "memory");
    __builtin_amdgcn_s_barrier();
    COMPUTE(1)

#undef STAGE
#undef COMPUTE

    // epilogue: C/D layout col=lane&15, row=(lane>>4)*4+reg (m89-verified)
    float b0v[4];
#pragma unroll
    for (int nt = 0; nt < 4; nt++) b0v[nt] = b0[n0 + wn * 64 + nt * 16 + lrow];
#pragma unroll
    for (int mt = 0; mt < 8; mt++) {
        const size_t rb = m0 + wm * 128 + mt * 16 + lquad * 4;
#pragma unroll
        for (int r = 0; r < 4; r++) {
            const size_t gm = rb + r;
            const int e0 = idxp[gm * 2 + 0], e1 = idxp[gm * 2 + 1];
            const float dd0 = dotp[gm * 2 + 0], dd1 = dotp[gm * 2 + 1];
#pragma unroll
            for (int nt = 0; nt < 4; nt++) {
                const size_t gn = n0 + wn * 64 + nt * 16 + lrow;
                float vv = acc[mt][nt][r] + b0v[nt]
                         + dd0 * uT[(size_t)e0 * N_OUT + gn] + dd1 * uT[(size_t)e1 * N_OUT + gn];
                out[gm * N_OUT + gn] = vv;
            }
        }
    }
}

extern "C" void kernel_launch(void* const* d_in, const int* in_sizes, int n_in,
                              void* d_out, int out_size, void* d_ws, size_t ws_size,
                              hipStream_t stream) {
    const float* x   = (const float*)d_in[0];  // [8192, 4096]
    const float* w0  = (const float*)d_in[1];  // [4096, 4096]
    const float* b0  = (const float*)d_in[2];  // [4096]
    const float* wr  = (const float*)d_in[3];  // [128, 4096]
    const float* u   = (const float*)d_in[4];  // [4096, 128]
    const float* svh = (const float*)d_in[5];  // [128, 4096]
    float* out = (float*)d_out;

    // workspace layout (~100.1 MiB total)
    char* ws = (char*)d_ws;
    unsigned short* xb  = (unsigned short*)ws;                       // 8192*4096*2  = 67108864 B
    unsigned short* w0b = (unsigned short*)(ws + 67108864);          // 4096*4096*2  = 33554432 B
    int*   idxp = (int*)(ws + 100663296);                            // 8192*2*4     = 65536 B
    float* dotp = (float*)(ws + 100663296 + 65536);                  // 8192*2*4     = 65536 B
    float* uTp  = (float*)(ws + 100663296 + 131072);                 // 128*4096*4   = 2097152 B
    unsigned short* wrh = (unsigned short*)(ws + 102891520);         // 128*4096*2   = 1048576 B
    unsigned short* wrl = (unsigned short*)(ws + 103940096);         // 128*4096*2   = 1048576 B

    k_convert_w0<<<dim3(16777216 / (256 * 8)), dim3(256), 0, stream>>>(w0, w0b);
    k_split_wr<<<dim3(N_POOL * K_DIM / (256 * 4)), dim3(256), 0, stream>>>(wr, wrh, wrl);
    k_transpose_u<<<dim3(N_OUT / 64, N_POOL / 32), dim3(256), 0, stream>>>(u, uTp);
    k_router<<<dim3(N_TOK / 32), dim3(512), 0, stream>>>(x, wr, wrh, wrl, svh, xb, idxp, dotp);
    k_gemm<<<dim3(512), dim3(512), 0, stream>>>(xb, w0b, b0, uTp, idxp, dotp, out);
}